// Round 11
// baseline (1077.689 us; speedup 1.0000x reference)
//
#include <hip/hip_runtime.h>

// NeuralODE SSP-RK3, z:[32,16,8192] fp32, W:[16,16,5], 100 steps, h=t/100.
// 20 dispatches x 5 fused RK steps (15 stages) via LDS halo recompute; conv =
// 3x mfma_f32_16x16x32_bf16 per 16-col tile (K-chunk = tap-pair x 16 in-ch);
// conv inputs/weights bf16 (LDS slab [col][ch]), state/pointwise fp32 in
// named registers (R10: no lambdas/arrays -> no scratch); BC via shuffles.
// R10 LESSON: transposed [x][ch] global stores ran at 4.25x WRITE_SIZE
// (quarter-wave = 16 lines x 16B partials); R2's row-major scalar stores
// (quarter-wave = one full 64B line) measured ideal. THIS ROUND: global state
// is ROW-MAJOR [b][ch][x] end-to-end; the [col][ch] transpose lives only in
// LDS staging. Transpose kernel + finalKer special case deleted.

#define NCH    16
#define LL     8192
#define TX     256
#define HALOC  32
#define SLABC  320          // 20 tiles of 16 cols; global x = x0 - 32 + s
#define NBX    32
#define NB     32
#define NSTEPS 100
#define SPK    5
#define NKER   (NSTEPS / SPK)

typedef __bf16 bf16x8 __attribute__((ext_vector_type(8)));
typedef __bf16 bf16x4 __attribute__((ext_vector_type(4)));
typedef float  f32x4  __attribute__((ext_vector_type(4)));

__device__ __forceinline__ int ldsIdx(int col, int ch) {
  return col * NCH + (ch ^ ((col & 4) << 1));
}

__device__ __forceinline__ bf16x8 mkA(const float* __restrict__ W, int c, int g, int n) {
  const int kk = c * 2 + (g >> 1);
  bf16x8 a;
#pragma unroll
  for (int j = 0; j < 8; ++j) {
    const int i = (g & 1) * 8 + j;
    a[j] = (__bf16)((kk < 5) ? W[n * (NCH * 5) + i * 5 + kk] : 0.0f);
  }
  return a;
}

// row-major state load: (x = x0-32+16t+n clamped, ch 4g..4g+3)
__device__ __forceinline__ f32x4 ldState(const float* __restrict__ zb, int x0,
                                         int t, int n, int g) {
  int gx = x0 - HALOC + 16 * t + n;
  gx = min(max(gx, 0), LL - 1);
  f32x4 v;
#pragma unroll
  for (int r = 0; r < 4; ++r) v[r] = zb[(size_t)(g * 4 + r) * LL + gx];
  return v;
}

// One 16-col tile of one RK stage. MODE 0: bf16 -> WS(LDS). MODE 1: row-major
// global store (quarter-wave = full 64B lines). UPDZ: kz <- v.
template<int MODE, bool UPDZ>
__device__ __forceinline__ void tileStage(
    int t, f32x4& KZ, f32x4& KF, float az, float ak, float agh,
    const __bf16* __restrict__ RS, __bf16* __restrict__ WS,
    bf16x8 af0, bf16x8 af1, bf16x8 af2,
    int lane, int g, int n, bool leftE, bool rightE,
    float* __restrict__ ob, int x0)
{
  f32x4 acc = {0.f, 0.f, 0.f, 0.f};
#pragma unroll
  for (int c = 0; c < 3; ++c) {
    const int kk = c * 2 + (g >> 1);
    int s = 16 * t + n + kk - 2;         // read col = write col + (kk-2)
    s = min(max(s, 0), SLABC - 1);
    const bf16x8 bfrag = *(const bf16x8*)(&RS[ldsIdx(s, (g & 1) * 8)]);
    const bf16x8 a = (c == 0) ? af0 : (c == 1) ? af1 : af2;
    acc = __builtin_amdgcn_mfma_f32_16x16x32_bf16(a, bfrag, acc, 0, 0, 0);
  }
  f32x4 v;
#pragma unroll
  for (int r = 0; r < 4; ++r) v[r] = az * KZ[r] + ak * KF[r] + agh * acc[r];

  // BC: x 0..9 <- x=10 (t=2, lane n=10); x 8182..8191 <- x=8181 (t=17, n=5)
  if (leftE && t == 2) {
#pragma unroll
    for (int r = 0; r < 4; ++r) {
      const float sv = __shfl(v[r], (lane & 48) | 10, 64);
      if (n < 10) v[r] = sv;
    }
  }
  if (rightE && t == 17) {
#pragma unroll
    for (int r = 0; r < 4; ++r) {
      const float sv = __shfl(v[r], (lane & 48) | 5, 64);
      if (n > 5) v[r] = sv;
    }
  }

  KF = v;
  if (UPDZ) KZ = v;

  if (MODE == 0) {
    bf16x4 bv = { (__bf16)v[0], (__bf16)v[1], (__bf16)v[2], (__bf16)v[3] };
    *(bf16x4*)(&WS[ldsIdx(16 * t + n, g * 4)]) = bv;
  } else {
    if (t >= 2 && t <= 17) {             // interior: xg in [x0, x0+256)
      const int xg = x0 - HALOC + 16 * t + n;
#pragma unroll
      for (int r = 0; r < 4; ++r) ob[(size_t)(g * 4 + r) * LL + xg] = v[r];
    }
  }
}

#define STAGE(az, ak, agh, UPDZ, MODE)                                          \
  do {                                                                          \
    const __bf16* RS_ = S[rb];                                                  \
    __bf16* WS_ = S[rb ^ 1];                                                    \
    tileStage<MODE, UPDZ>(wv +  0, kz0, kf0, az, ak, agh, RS_, WS_, af0, af1,   \
                          af2, lane, g, n, leftE, rightE, ob, x0);              \
    tileStage<MODE, UPDZ>(wv +  4, kz1, kf1, az, ak, agh, RS_, WS_, af0, af1,   \
                          af2, lane, g, n, leftE, rightE, ob, x0);              \
    tileStage<MODE, UPDZ>(wv +  8, kz2, kf2, az, ak, agh, RS_, WS_, af0, af1,   \
                          af2, lane, g, n, leftE, rightE, ob, x0);              \
    tileStage<MODE, UPDZ>(wv + 12, kz3, kf3, az, ak, agh, RS_, WS_, af0, af1,   \
                          af2, lane, g, n, leftE, rightE, ob, x0);              \
    tileStage<MODE, UPDZ>(wv + 16, kz4, kf4, az, ak, agh, RS_, WS_, af0, af1,   \
                          af2, lane, g, n, leftE, rightE, ob, x0);              \
  } while (0)

__global__ __launch_bounds__(256, 4) void multistep_kernel(
    const float* __restrict__ zin,   // fp32 row-major [b][ch][x]
    float* __restrict__ zout,        // fp32 row-major [b][ch][x]
    const float* __restrict__ W,     // [o][i][k] 16x16x5
    const int* __restrict__ tptr)
{
  __shared__ __align__(16) __bf16 S[2][SLABC * NCH];

  const int b = blockIdx.y, bx = blockIdx.x;
  const int x0 = bx * TX;
  const bool leftE = (bx == 0), rightE = (bx == NBX - 1);
  const float h = (float)(*tptr) / (float)NSTEPS;
  const int tid = threadIdx.x, lane = tid & 63, wv = tid >> 6;
  const int g = lane >> 4, n = lane & 15;

  const float* __restrict__ zb = zin + (size_t)b * NCH * LL;
  float* __restrict__ ob = zout + (size_t)b * NCH * LL;

  const bf16x8 af0 = mkA(W, 0, g, n);
  const bf16x8 af1 = mkA(W, 1, g, n);
  const bf16x8 af2 = mkA(W, 2, g, n);

  // Slab load: row-major global -> bf16 [col][ch] LDS (transpose in LDS).
  // 1280 float4-chunks (80 per ch row); consecutive lanes = consecutive
  // chunks -> coalesced dwordx4 interior, clamped scalars at domain edges.
#pragma unroll
  for (int it = 0; it < 5; ++it) {
    const int idx = it * 256 + tid;
    const int ch = idx / 80;
    const int xc = idx - ch * 80;
    const int sb = xc * 4;
    const float* __restrict__ row = zb + (size_t)ch * LL;
    const int gx0 = x0 - HALOC + sb;
    float e0, e1, e2, e3;
    if (gx0 >= 0 && gx0 + 3 < LL) {
      const float4 v = *(const float4*)(row + gx0);
      e0 = v.x; e1 = v.y; e2 = v.z; e3 = v.w;
    } else {
      e0 = row[min(max(gx0 + 0, 0), LL - 1)];
      e1 = row[min(max(gx0 + 1, 0), LL - 1)];
      e2 = row[min(max(gx0 + 2, 0), LL - 1)];
      e3 = row[min(max(gx0 + 3, 0), LL - 1)];
    }
    S[0][ldsIdx(sb + 0, ch)] = (__bf16)e0;
    S[0][ldsIdx(sb + 1, ch)] = (__bf16)e1;
    S[0][ldsIdx(sb + 2, ch)] = (__bf16)e2;
    S[0][ldsIdx(sb + 3, ch)] = (__bf16)e3;
  }

  // fp32 state in named registers (same lines as slab -> L1/L2 hits).
  f32x4 kz0 = ldState(zb, x0, wv +  0, n, g);
  f32x4 kz1 = ldState(zb, x0, wv +  4, n, g);
  f32x4 kz2 = ldState(zb, x0, wv +  8, n, g);
  f32x4 kz3 = ldState(zb, x0, wv + 12, n, g);
  f32x4 kz4 = ldState(zb, x0, wv + 16, n, g);
  f32x4 kf0 = {0.f,0.f,0.f,0.f}, kf1 = kf0, kf2 = kf0, kf3 = kf0, kf4 = kf0;
  __syncthreads();

  const float c13 = 1.0f / 3.0f, c23 = 2.0f / 3.0f;
  int rb = 0;
#pragma unroll 1
  for (int sp = 0; sp < SPK; ++sp) {
    STAGE(1.0f, 0.0f, h, false, 0);
    __syncthreads(); rb ^= 1;
    STAGE(0.75f, 0.25f, 0.25f * h, false, 0);
    __syncthreads(); rb ^= 1;
    if (sp != SPK - 1) {
      STAGE(c13, c23, c23 * h, true, 0);
      __syncthreads(); rb ^= 1;
    } else {
      STAGE(c13, c23, c23 * h, true, 1);
    }
  }
}

extern "C" void kernel_launch(void* const* d_in, const int* in_sizes, int n_in,
                              void* d_out, int out_size, void* d_ws, size_t ws_size,
                              hipStream_t stream) {
  const float* z0 = (const float*)d_in[0];
  const float* W  = (const float*)d_in[1];
  const int*   t  = (const int*)d_in[2];

  float* Q = (float*)d_out;   // row-major; final dispatch (k=20, even) lands here
  float* P = (float*)d_ws;    // 16 MiB row-major scratch

  dim3 grid(NBX, NB), block(256);
  for (int k = 1; k <= NKER; ++k) {
    const float* in = (k == 1) ? z0 : ((k & 1) ? Q : P);
    float* out = (k & 1) ? P : Q;
    multistep_kernel<<<grid, block, 0, stream>>>(in, out, W, t);
  }
}

// Round 12
// 920.946 us; speedup vs baseline: 1.1702x; 1.1702x over previous
//
#include <hip/hip_runtime.h>

// NeuralODE SSP-RK3, z:[32,16,8192] fp32, W:[16,16,5], 100 steps, h=t/100.
// R10 structure (best: 924us): 20 dispatches x 5 fused RK steps (15 stages)
// via LDS halo recompute; transposed fp32 state [b][x][ch]; conv = 3x
// mfma_f32_16x16x32_bf16 per 16-col tile (K-chunk = tap-pair x 16 in-ch);
// conv inputs/weights bf16, state/pointwise fp32 in named registers; BC via
// in-wave shuffles.
// R12 CHANGE (single variable): pin amdgpu_waves_per_eu(4,4). Evidence:
// every MFMA round reported VGPR_Count=64 (=512/8: backend targeting 8
// waves/EU) and a WRITE excess of ~52MiB/dispatch = exactly 208B/thread =
// kz0..4+kf0..4+af0..2 (52 dwords) spilled to scratch and evicted dirty.
// R11 disproved the store-pattern theory (row-major stores kept the excess).
// Pinning 4 waves/EU gives the allocator the full 128-VGPR budget.

#define NCH    16
#define LL     8192
#define TX     256
#define HALOC  32
#define SLABC  320          // 20 tiles of 16 cols; global x = x0 - 32 + s
#define NBX    32
#define NB     32
#define NSTEPS 100
#define SPK    5
#define NKER   (NSTEPS / SPK)

typedef __bf16 bf16x8 __attribute__((ext_vector_type(8)));
typedef __bf16 bf16x4 __attribute__((ext_vector_type(4)));
typedef float  f32x4  __attribute__((ext_vector_type(4)));

__device__ __forceinline__ int ldsIdx(int col, int ch) {
  return col * NCH + (ch ^ ((col & 4) << 1));
}

__global__ __launch_bounds__(256) void transpose_kernel(const float* __restrict__ in,
                                                        float* __restrict__ out) {
  const int b = blockIdx.y;
  const int x = blockIdx.x * 256 + threadIdx.x;
  const float* __restrict__ ib = in + (size_t)b * NCH * LL;
  float* __restrict__ ob = out + (size_t)b * NCH * LL;
  float v[NCH];
#pragma unroll
  for (int c = 0; c < NCH; ++c) v[c] = ib[c * LL + x];
#pragma unroll
  for (int c = 0; c < NCH; c += 4)
    *(float4*)(ob + (size_t)x * NCH + c) = make_float4(v[c], v[c+1], v[c+2], v[c+3]);
}

__device__ __forceinline__ bf16x8 mkA(const float* __restrict__ W, int c, int g, int n) {
  const int kk = c * 2 + (g >> 1);
  bf16x8 a;
#pragma unroll
  for (int j = 0; j < 8; ++j) {
    const int i = (g & 1) * 8 + j;
    a[j] = (__bf16)((kk < 5) ? W[n * (NCH * 5) + i * 5 + kk] : 0.0f);
  }
  return a;
}

__device__ __forceinline__ f32x4 ldState(const float* __restrict__ zb, int x0,
                                         int t, int n, int g) {
  int gx = x0 - HALOC + 16 * t + n;
  gx = min(max(gx, 0), LL - 1);
  return *(const f32x4*)(zb + (size_t)gx * NCH + g * 4);
}

// One 16-col tile of one RK stage. MODE 0: bf16 -> WS(LDS). MODE 1: global
// store (transposed fp32, or row-major if finalKer). UPDZ: kz <- v.
template<int MODE, bool UPDZ>
__device__ __forceinline__ void tileStage(
    int t, f32x4& KZ, f32x4& KF, float az, float ak, float agh,
    const __bf16* __restrict__ RS, __bf16* __restrict__ WS,
    bf16x8 af0, bf16x8 af1, bf16x8 af2,
    int lane, int g, int n, bool leftE, bool rightE,
    float* __restrict__ ob, int x0, int finalKer)
{
  f32x4 acc = {0.f, 0.f, 0.f, 0.f};
#pragma unroll
  for (int c = 0; c < 3; ++c) {
    const int kk = c * 2 + (g >> 1);
    int s = 16 * t + n + kk - 2;         // read col = write col + (kk-2)
    s = min(max(s, 0), SLABC - 1);
    const bf16x8 bfrag = *(const bf16x8*)(&RS[ldsIdx(s, (g & 1) * 8)]);
    const bf16x8 a = (c == 0) ? af0 : (c == 1) ? af1 : af2;
    acc = __builtin_amdgcn_mfma_f32_16x16x32_bf16(a, bfrag, acc, 0, 0, 0);
  }
  f32x4 v;
#pragma unroll
  for (int r = 0; r < 4; ++r) v[r] = az * KZ[r] + ak * KF[r] + agh * acc[r];

  // BC: x 0..9 <- x=10 (t=2, lane n=10); x 8182..8191 <- x=8181 (t=17, n=5)
  if (leftE && t == 2) {
#pragma unroll
    for (int r = 0; r < 4; ++r) {
      const float sv = __shfl(v[r], (lane & 48) | 10, 64);
      if (n < 10) v[r] = sv;
    }
  }
  if (rightE && t == 17) {
#pragma unroll
    for (int r = 0; r < 4; ++r) {
      const float sv = __shfl(v[r], (lane & 48) | 5, 64);
      if (n > 5) v[r] = sv;
    }
  }

  KF = v;
  if (UPDZ) KZ = v;

  if (MODE == 0) {
    bf16x4 bv = { (__bf16)v[0], (__bf16)v[1], (__bf16)v[2], (__bf16)v[3] };
    *(bf16x4*)(&WS[ldsIdx(16 * t + n, g * 4)]) = bv;
  } else {
    if (t >= 2 && t <= 17) {             // interior: gx in [x0, x0+256)
      const int xg = x0 - HALOC + 16 * t + n;
      if (!finalKer) {
        *(f32x4*)(ob + (size_t)xg * NCH + g * 4) = v;
      } else {
#pragma unroll
        for (int r = 0; r < 4; ++r) ob[(size_t)(g * 4 + r) * LL + xg] = v[r];
      }
    }
  }
}

#define STAGE(az, ak, agh, UPDZ, MODE)                                          \
  do {                                                                          \
    const __bf16* RS_ = S[rb];                                                  \
    __bf16* WS_ = S[rb ^ 1];                                                    \
    tileStage<MODE, UPDZ>(wv +  0, kz0, kf0, az, ak, agh, RS_, WS_, af0, af1,   \
                          af2, lane, g, n, leftE, rightE, ob, x0, finalKer);    \
    tileStage<MODE, UPDZ>(wv +  4, kz1, kf1, az, ak, agh, RS_, WS_, af0, af1,   \
                          af2, lane, g, n, leftE, rightE, ob, x0, finalKer);    \
    tileStage<MODE, UPDZ>(wv +  8, kz2, kf2, az, ak, agh, RS_, WS_, af0, af1,   \
                          af2, lane, g, n, leftE, rightE, ob, x0, finalKer);    \
    tileStage<MODE, UPDZ>(wv + 12, kz3, kf3, az, ak, agh, RS_, WS_, af0, af1,   \
                          af2, lane, g, n, leftE, rightE, ob, x0, finalKer);    \
    tileStage<MODE, UPDZ>(wv + 16, kz4, kf4, az, ak, agh, RS_, WS_, af0, af1,   \
                          af2, lane, g, n, leftE, rightE, ob, x0, finalKer);    \
  } while (0)

__global__ __launch_bounds__(256)
__attribute__((amdgpu_waves_per_eu(4, 4)))
void multistep_kernel(
    const float* __restrict__ zin,   // fp32 transposed [b][x][ch]
    float* __restrict__ zout,        // fp32 transposed (row-major if finalKer)
    const float* __restrict__ W,     // [o][i][k] 16x16x5
    const int* __restrict__ tptr, int finalKer)
{
  __shared__ __align__(16) __bf16 S[2][SLABC * NCH];

  const int b = blockIdx.y, bx = blockIdx.x;
  const int x0 = bx * TX;
  const bool leftE = (bx == 0), rightE = (bx == NBX - 1);
  const float h = (float)(*tptr) / (float)NSTEPS;
  const int tid = threadIdx.x, lane = tid & 63, wv = tid >> 6;
  const int g = lane >> 4, n = lane & 15;

  const float* __restrict__ zb = zin + (size_t)b * NCH * LL;
  float* __restrict__ ob = zout + (size_t)b * NCH * LL;

  const bf16x8 af0 = mkA(W, 0, g, n);
  const bf16x8 af1 = mkA(W, 1, g, n);
  const bf16x8 af2 = mkA(W, 2, g, n);

  // Load z slab -> S[0] (bf16, swizzled); coalesced (4 threads per 64B line).
  for (int q = tid; q < SLABC * 4; q += 256) {
    const int s = q >> 2, cg = (q & 3) * 4;
    int gx = x0 - HALOC + s;
    gx = min(max(gx, 0), LL - 1);
    const float4 v = *(const float4*)(zb + (size_t)gx * NCH + cg);
    bf16x4 bv = { (__bf16)v.x, (__bf16)v.y, (__bf16)v.z, (__bf16)v.w };
    *(bf16x4*)(&S[0][ldsIdx(s, cg)]) = bv;
  }

  // fp32 state in named registers: thread owns (x=16t+n, ch 4g..4g+3), t=wv+4ti.
  f32x4 kz0 = ldState(zb, x0, wv +  0, n, g);
  f32x4 kz1 = ldState(zb, x0, wv +  4, n, g);
  f32x4 kz2 = ldState(zb, x0, wv +  8, n, g);
  f32x4 kz3 = ldState(zb, x0, wv + 12, n, g);
  f32x4 kz4 = ldState(zb, x0, wv + 16, n, g);
  f32x4 kf0 = {0.f,0.f,0.f,0.f}, kf1 = kf0, kf2 = kf0, kf3 = kf0, kf4 = kf0;
  __syncthreads();

  const float c13 = 1.0f / 3.0f, c23 = 2.0f / 3.0f;
  int rb = 0;
#pragma unroll 1
  for (int sp = 0; sp < SPK; ++sp) {
    STAGE(1.0f, 0.0f, h, false, 0);
    __syncthreads(); rb ^= 1;
    STAGE(0.75f, 0.25f, 0.25f * h, false, 0);
    __syncthreads(); rb ^= 1;
    if (sp != SPK - 1) {
      STAGE(c13, c23, c23 * h, true, 0);
      __syncthreads(); rb ^= 1;
    } else {
      STAGE(c13, c23, c23 * h, true, 1);
    }
  }
}

extern "C" void kernel_launch(void* const* d_in, const int* in_sizes, int n_in,
                              void* d_out, int out_size, void* d_ws, size_t ws_size,
                              hipStream_t stream) {
  const float* z0 = (const float*)d_in[0];
  const float* W  = (const float*)d_in[1];
  const int*   t  = (const int*)d_in[2];

  float* Q = (float*)d_out;   // transposed intermediate; final row-major dest
  float* P = (float*)d_ws;    // 16 MiB scratch

  dim3 grid(NBX, NB), block(256);
  transpose_kernel<<<grid, block, 0, stream>>>(z0, Q);

  for (int k = 1; k <= NKER; ++k) {
    if (k & 1) multistep_kernel<<<grid, block, 0, stream>>>(Q, P, W, t, 0);
    else       multistep_kernel<<<grid, block, 0, stream>>>(P, Q, W, t, k == NKER);
  }
}